// Round 3
// baseline (1550.623 us; speedup 1.0000x reference)
//
#include <hip/hip_runtime.h>
#include <hip/hip_bf16.h>
#include <stdint.h>

// W8Linear: out[m][n] = sum_k x[m][k] * wq[n][k] * max_val[n]/127
constexpr int Mdim = 8192;
constexpr int Kdim = 4096;
constexpr int Ndim = 11008;

typedef _Float16 f16x8 __attribute__((ext_vector_type(8)));
typedef _Float16 f16x4 __attribute__((ext_vector_type(4)));
typedef float    f32x4 __attribute__((ext_vector_type(4)));
typedef int      i32x4 __attribute__((ext_vector_type(4)));

// ---------------- converts: fp32 -> f16, int32 -> f16 (exact for |v|<=127) ----

__global__ __launch_bounds__(256) void cvt_f32_f16(const float* __restrict__ in,
                                                   _Float16* __restrict__ out,
                                                   int nvec8) {
  int idx = blockIdx.x * blockDim.x + threadIdx.x;
  int stride = gridDim.x * blockDim.x;
  for (int i = idx; i < nvec8; i += stride) {
    const f32x4* p = (const f32x4*)in + (size_t)i * 2;
    f32x4 a = p[0];
    f32x4 b = p[1];
    f16x8 h;
    h[0] = (_Float16)a[0]; h[1] = (_Float16)a[1];
    h[2] = (_Float16)a[2]; h[3] = (_Float16)a[3];
    h[4] = (_Float16)b[0]; h[5] = (_Float16)b[1];
    h[6] = (_Float16)b[2]; h[7] = (_Float16)b[3];
    ((f16x8*)out)[i] = h;
  }
}

__global__ __launch_bounds__(256) void cvt_i32_f16(const int* __restrict__ in,
                                                   _Float16* __restrict__ out,
                                                   int nvec8) {
  int idx = blockIdx.x * blockDim.x + threadIdx.x;
  int stride = gridDim.x * blockDim.x;
  for (int i = idx; i < nvec8; i += stride) {
    const i32x4* p = (const i32x4*)in + (size_t)i * 2;
    i32x4 a = p[0];
    i32x4 b = p[1];
    f16x8 h;
    h[0] = (_Float16)a[0]; h[1] = (_Float16)a[1];
    h[2] = (_Float16)a[2]; h[3] = (_Float16)a[3];
    h[4] = (_Float16)b[0]; h[5] = (_Float16)b[1];
    h[6] = (_Float16)b[2]; h[7] = (_Float16)b[3];
    ((f16x8*)out)[i] = h;
  }
}

// ---------------- async global->LDS, 16B per lane -----------------------------

__device__ __forceinline__ void gl_lds16(const _Float16* g, _Float16* l) {
  __builtin_amdgcn_global_load_lds(
      (const __attribute__((address_space(1))) unsigned int*)g,
      (__attribute__((address_space(3))) unsigned int*)l,
      16, 0, 0);
}

#define WAITV4()    asm volatile("s_waitcnt vmcnt(4)" ::: "memory")
#define WAITV0()    asm volatile("s_waitcnt vmcnt(0)" ::: "memory")
#define WAITLGKM0() asm volatile("s_waitcnt lgkmcnt(0)" ::: "memory")
#define SBAR()      __builtin_amdgcn_s_barrier()
#define SCHED0()    __builtin_amdgcn_sched_barrier(0)
#define MFMA16(d, va, vb) d = __builtin_amdgcn_mfma_f32_16x16x32_f16(va, vb, d, 0, 0, 0)

// =============================================================================
// 256x256 tile, BK=32, 8 waves (2M x 4N), 3-buffer LDS pipeline (96 KiB).
//
// Schedule per K-tile T (2 phases, 16 MFMA each):
//   ph1: STAGE A-halves of tile T+2 -> buf[(T+2)%3]; ds_read A m0-3 + B n0-3
//        of buf[T%3]; s_barrier; lgkmcnt(0); setprio(1); 16 MFMA; setprio(0);
//        s_barrier
//   ph2: STAGE B-halves of T+2; ds_read A m4-7; s_barrier; lgkmcnt(0);
//        setprio(1); 16 MFMA; setprio(0); vmcnt(4); s_barrier
//
// Race-freedom (barrier-ordered, no latency assumptions): tile T+2's buffer
// was last READ by tile T-1; every phase does lgkmcnt(0) before MFMA and
// barrier after, so all T-1 reads COMPLETED before the end-of-(T-1) barrier;
// T+2's stages are issued after that barrier. Landing is enforced by
// per-wave vmcnt(4) (tile T+1's 4 loads are the oldest outstanding) followed
// by s_barrier, so every wave's stages have landed before any wave reads.
// vmcnt never drains to 0 in steady state (T3/T4 counted-vmcnt pipeline).
//
// LDS swizzle (T2, rule #21 both-sides): 64 B rows, 4x16B slots/row.
// slot' = slot ^ ((row>>2)&3). Write side: linear gl_lds dest, inverse-
// swizzled GLOBAL source (thread t sources k-chunk (t&3)^((row>>2)&3)).
// Read side: ds_read_b128 at byte = row*64 + ((kgrp ^ ((row>>2)&3))<<4).
// Per 16-lane group this lands 2 lanes/bank-group = free (m136).
// =============================================================================

constexpr int BM = 256, BN = 256, BK = 32;
constexpr int NT = Kdim / BK;  // 128

__global__ __launch_bounds__(512, 2) void w8_gemm256(
    const _Float16* __restrict__ A, const _Float16* __restrict__ Bw,
    const float* __restrict__ maxval, float* __restrict__ C) {
  __shared__ _Float16 As[3][BM][BK];  // 3 x 16 KiB
  __shared__ _Float16 Bs[3][BM][BK];  // 3 x 16 KiB

  const int nbn = Ndim / BN;                    // 43
  const int cpx = ((Mdim / BM) * nbn) / 8;      // 1376/8 = 172 (bijective: 1376%8==0)
  int bid = blockIdx.x;
  bid = (bid & 7) * cpx + (bid >> 3);           // XCD-aware swizzle (T1)
  const int rowBase = (bid / nbn) * BM;
  const int colBase = (bid % nbn) * BN;

  const int t = threadIdx.x;
  const int lane = t & 63;
  const int wid = t >> 6;        // 0..7
  const int wr = wid >> 2;       // 0..1  (owns 128 output rows)
  const int wc = wid & 3;        // 0..3  (owns 64 output cols)
  const int lrow = lane & 15;
  const int kgrp = lane >> 4;    // 0..3

  // Staging: thread t owns LDS 16B slot t of each 8 KiB half-tile
  // (row sr = t>>2, slot t&3). Global source chunk is inverse-swizzled.
  const int sr = t >> 2;                              // 0..127
  const int sc = ((t & 3) ^ ((sr >> 2) & 3)) << 3;    // k-elem offset 0/8/16/24
  const size_t aRow0 = (size_t)(rowBase + sr) * Kdim + sc;
  const size_t aRow1 = (size_t)(rowBase + 128 + sr) * Kdim + sc;
  const size_t bRow0 = (size_t)(colBase + sr) * Kdim + sc;
  const size_t bRow1 = (size_t)(colBase + 128 + sr) * Kdim + sc;
  const int ldsOff = t * 8;  // f16 units; +4096 for half 1

#define STAGE_A(buf, k0) do { \
    gl_lds16(A + aRow0 + (k0), (_Float16*)As[buf] + ldsOff); \
    gl_lds16(A + aRow1 + (k0), (_Float16*)As[buf] + 4096 + ldsOff); } while (0)
#define STAGE_B(buf, k0) do { \
    gl_lds16(Bw + bRow0 + (k0), (_Float16*)Bs[buf] + ldsOff); \
    gl_lds16(Bw + bRow1 + (k0), (_Float16*)Bs[buf] + 4096 + ldsOff); } while (0)

  // Swizzled ds_read byte offsets (constant-indexed -> registers)
  int offA[8], offB[4];
#pragma unroll
  for (int m = 0; m < 8; ++m) {
    int rt = wr * 128 + m * 16 + lrow;
    offA[m] = rt * 64 + ((kgrp ^ ((rt >> 2) & 3)) << 4);
  }
#pragma unroll
  for (int n = 0; n < 4; ++n) {
    int rt = wc * 64 + n * 16 + lrow;
    offB[n] = rt * 64 + ((kgrp ^ ((rt >> 2) & 3)) << 4);
  }

#define RDA(buf, m) (*(const f16x8*)((const char*)&As[buf][0][0] + offA[m]))
#define RDB(buf, n) (*(const f16x8*)((const char*)&Bs[buf][0][0] + offB[n]))

  f32x4 acc[8][4] = {};

  // Prologue: tile0 -> buf0, tile1 -> buf1 (8 loads); tile0 landed, tile1 in flight.
  STAGE_A(0, 0); STAGE_B(0, 0);
  STAGE_A(1, BK); STAGE_B(1, BK);
  WAITV4();
  SBAR();

  int cur = 0, nx1 = 1, nx2 = 2;
  for (int T = 0; T < NT; ++T) {
    const int kst = (T + 2) * BK;
    // ---- phase 1: stage A(T+2); read A m0-3 + B n0-3; MFMA m0-3 x n0-3
    if (T + 2 < NT) STAGE_A(nx2, kst);
    f16x8 a0 = RDA(cur, 0), a1 = RDA(cur, 1), a2 = RDA(cur, 2), a3 = RDA(cur, 3);
    f16x8 b0 = RDB(cur, 0), b1 = RDB(cur, 1), b2 = RDB(cur, 2), b3 = RDB(cur, 3);
    SBAR();
    WAITLGKM0();
    SCHED0();
    __builtin_amdgcn_s_setprio(1);
    MFMA16(acc[0][0], a0, b0); MFMA16(acc[0][1], a0, b1); MFMA16(acc[0][2], a0, b2); MFMA16(acc[0][3], a0, b3);
    MFMA16(acc[1][0], a1, b0); MFMA16(acc[1][1], a1, b1); MFMA16(acc[1][2], a1, b2); MFMA16(acc[1][3], a1, b3);
    MFMA16(acc[2][0], a2, b0); MFMA16(acc[2][1], a2, b1); MFMA16(acc[2][2], a2, b2); MFMA16(acc[2][3], a2, b3);
    MFMA16(acc[3][0], a3, b0); MFMA16(acc[3][1], a3, b1); MFMA16(acc[3][2], a3, b2); MFMA16(acc[3][3], a3, b3);
    __builtin_amdgcn_s_setprio(0);
    SBAR();
    // ---- phase 2: stage B(T+2); read A m4-7; MFMA m4-7 x n0-3 (reuse b0-3)
    if (T + 2 < NT) STAGE_B(nx2, kst);
    f16x8 a4 = RDA(cur, 4), a5 = RDA(cur, 5), a6 = RDA(cur, 6), a7 = RDA(cur, 7);
    SBAR();
    WAITLGKM0();
    SCHED0();
    __builtin_amdgcn_s_setprio(1);
    MFMA16(acc[4][0], a4, b0); MFMA16(acc[4][1], a4, b1); MFMA16(acc[4][2], a4, b2); MFMA16(acc[4][3], a4, b3);
    MFMA16(acc[5][0], a5, b0); MFMA16(acc[5][1], a5, b1); MFMA16(acc[5][2], a5, b2); MFMA16(acc[5][3], a5, b3);
    MFMA16(acc[6][0], a6, b0); MFMA16(acc[6][1], a6, b1); MFMA16(acc[6][2], a6, b2); MFMA16(acc[6][3], a6, b3);
    MFMA16(acc[7][0], a7, b0); MFMA16(acc[7][1], a7, b1); MFMA16(acc[7][2], a7, b2); MFMA16(acc[7][3], a7, b3);
    __builtin_amdgcn_s_setprio(0);
    // end-of-tile: ensure T+1 fully landed (its 4 loads are oldest outstanding);
    // tail tiles (no more stages issued) must drain fully.
    if (T < NT - 2) { WAITV4(); } else { WAITV0(); }
    SBAR();
    int tmp = cur; cur = nx1; nx1 = nx2; nx2 = tmp;
  }

  // Epilogue: C/D layout col=lane&15, row=(lane>>4)*4+reg (m89-verified).
  float s[4];
#pragma unroll
  for (int n = 0; n < 4; ++n)
    s[n] = maxval[colBase + wc * 64 + n * 16 + lrow] * (1.0f / 127.0f);
#pragma unroll
  for (int m = 0; m < 8; ++m) {
#pragma unroll
    for (int j = 0; j < 4; ++j) {
      int row = rowBase + wr * 128 + m * 16 + kgrp * 4 + j;
      float* cp = C + (size_t)row * Ndim + colBase + wc * 64 + lrow;
#pragma unroll
      for (int n = 0; n < 4; ++n)
        cp[n * 16] = acc[m][n][j] * s[n];
    }
  }
#undef STAGE_A
#undef STAGE_B
#undef RDA
#undef RDB
}

// ---------------- fallback (ws too small): 128^2 reg-staged convert-in-GEMM ---

__global__ __launch_bounds__(256) void w8_gemm_fb(const float* __restrict__ A,
                                                  const int* __restrict__ Bw,
                                                  const float* __restrict__ maxval,
                                                  float* __restrict__ C) {
  __shared__ _Float16 Asb[128][32];
  __shared__ _Float16 Bsb[128][32];
  const int nbn = Ndim / 128;
  const int cpx = ((Mdim / 128) * nbn) / 8;
  int bid = blockIdx.x;
  bid = (bid & 7) * cpx + (bid >> 3);
  const int rowBase = (bid / nbn) * 128;
  const int colBase = (bid % nbn) * 128;
  const int t = threadIdx.x;
  const int lane = t & 63;
  const int wid = t >> 6;
  const int wr = wid >> 1, wc = wid & 1;
  const int lrow = lane & 15, kgrp = lane >> 4;
  f32x4 acc[4][4] = {};
  for (int k0 = 0; k0 < Kdim; k0 += 32) {
    __syncthreads();
#pragma unroll
    for (int i = 0; i < 4; ++i) {
      int c = i * 256 + t;
      int r = c >> 3;
      int ce = (c & 7) * 4;
      f32x4 av = *(const f32x4*)(A + (size_t)(rowBase + r) * Kdim + k0 + ce);
      i32x4 bv = *(const i32x4*)(Bw + (size_t)(colBase + r) * Kdim + k0 + ce);
      f16x4 ah, bh;
#pragma unroll
      for (int j = 0; j < 4; ++j) { ah[j] = (_Float16)av[j]; bh[j] = (_Float16)bv[j]; }
      *(f16x4*)&Asb[r][ce] = ah;
      *(f16x4*)&Bsb[r][ce] = bh;
    }
    __syncthreads();
    f16x8 a[4], b[4];
#pragma unroll
    for (int m = 0; m < 4; ++m) a[m] = *(const f16x8*)&Asb[wr * 64 + m * 16 + lrow][kgrp * 8];
#pragma unroll
    for (int n = 0; n < 4; ++n) b[n] = *(const f16x8*)&Bsb[wc * 64 + n * 16 + lrow][kgrp * 8];
#pragma unroll
    for (int m = 0; m < 4; ++m)
#pragma unroll
      for (int n = 0; n < 4; ++n)
        acc[m][n] = __builtin_amdgcn_mfma_f32_16x16x32_f16(a[m], b[n], acc[m][n], 0, 0, 0);
  }
  float s[4];
#pragma unroll
  for (int n = 0; n < 4; ++n)
    s[n] = maxval[colBase + wc * 64 + n * 16 + lrow] * (1.0f / 127.0f);
#pragma unroll
  for (int m = 0; m < 4; ++m)
#pragma unroll
    for (int j = 0; j < 4; ++j) {
      int row = rowBase + wr * 64 + m * 16 + kgrp * 4 + j;
      float* cp = C + (size_t)row * Ndim + colBase + wc * 64 + lrow;
#pragma unroll
      for (int n = 0; n < 4; ++n) cp[n * 16] = acc[m][n][j] * s[n];
    }
}

// ---------------- launch ------------------------------------------------------

extern "C" void kernel_launch(void* const* d_in, const int* in_sizes, int n_in,
                              void* d_out, int out_size, void* d_ws, size_t ws_size,
                              hipStream_t stream) {
  const float* x  = (const float*)d_in[0];   // [8192, 4096] fp32
  const int*   wq = (const int*)d_in[1];     // [11008, 4096] int32
  const float* mx = (const float*)d_in[2];   // [11008] fp32
  float* out = (float*)d_out;                // [8192, 11008] fp32

  const size_t xh_bytes = (size_t)Mdim * Kdim * sizeof(_Float16);  // 64 MiB
  const size_t wh_bytes = (size_t)Ndim * Kdim * sizeof(_Float16);  // 86 MiB

  if (ws_size >= xh_bytes + wh_bytes) {
    _Float16* xh = (_Float16*)d_ws;
    _Float16* wh = (_Float16*)((char*)d_ws + xh_bytes);
    cvt_f32_f16<<<2048, 256, 0, stream>>>(x, xh, Mdim * Kdim / 8);
    cvt_i32_f16<<<2048, 256, 0, stream>>>(wq, wh, Ndim * Kdim / 8);
    const int nblocks = (Mdim / BM) * (Ndim / BN);  // 1376
    w8_gemm256<<<nblocks, 512, 0, stream>>>(xh, wh, mx, out);
  } else {
    const int nblocks = (Mdim / 128) * (Ndim / 128);
    w8_gemm_fb<<<nblocks, 256, 0, stream>>>(x, wq, mx, out);
  }
}

// Round 5
// 1527.637 us; speedup vs baseline: 1.0150x; 1.0150x over previous
//
#include <hip/hip_runtime.h>
#include <hip/hip_bf16.h>
#include <stdint.h>

// W8Linear: out[m][n] = sum_k x[m][k] * wq[n][k] * max_val[n]/127
constexpr int Mdim = 8192;
constexpr int Kdim = 4096;
constexpr int Ndim = 11008;

typedef _Float16 f16x8 __attribute__((ext_vector_type(8)));
typedef _Float16 f16x4 __attribute__((ext_vector_type(4)));
typedef float    f32x4 __attribute__((ext_vector_type(4)));
typedef int      i32x4 __attribute__((ext_vector_type(4)));

// ---------------- converts: fp32 -> f16, int32 -> f16 (exact for |v|<=127) ----

__global__ __launch_bounds__(256) void cvt_f32_f16(const float* __restrict__ in,
                                                   _Float16* __restrict__ out,
                                                   int nvec8) {
  int idx = blockIdx.x * blockDim.x + threadIdx.x;
  int stride = gridDim.x * blockDim.x;
  for (int i = idx; i < nvec8; i += stride) {
    const f32x4* p = (const f32x4*)in + (size_t)i * 2;
    f32x4 a = p[0];
    f32x4 b = p[1];
    f16x8 h;
    h[0] = (_Float16)a[0]; h[1] = (_Float16)a[1];
    h[2] = (_Float16)a[2]; h[3] = (_Float16)a[3];
    h[4] = (_Float16)b[0]; h[5] = (_Float16)b[1];
    h[6] = (_Float16)b[2]; h[7] = (_Float16)b[3];
    ((f16x8*)out)[i] = h;
  }
}

__global__ __launch_bounds__(256) void cvt_i32_f16(const int* __restrict__ in,
                                                   _Float16* __restrict__ out,
                                                   int nvec8) {
  int idx = blockIdx.x * blockDim.x + threadIdx.x;
  int stride = gridDim.x * blockDim.x;
  for (int i = idx; i < nvec8; i += stride) {
    const i32x4* p = (const i32x4*)in + (size_t)i * 2;
    i32x4 a = p[0];
    i32x4 b = p[1];
    f16x8 h;
    h[0] = (_Float16)a[0]; h[1] = (_Float16)a[1];
    h[2] = (_Float16)a[2]; h[3] = (_Float16)a[3];
    h[4] = (_Float16)b[0]; h[5] = (_Float16)b[1];
    h[6] = (_Float16)b[2]; h[7] = (_Float16)b[3];
    ((f16x8*)out)[i] = h;
  }
}

// ---------------- async global->LDS, 16B per lane -----------------------------

__device__ __forceinline__ void gl_lds16(const _Float16* g, _Float16* l) {
  __builtin_amdgcn_global_load_lds(
      (const __attribute__((address_space(1))) unsigned int*)g,
      (__attribute__((address_space(3))) unsigned int*)l,
      16, 0, 0);
}

#define WAITV8()    asm volatile("s_waitcnt vmcnt(8)" ::: "memory")
#define WAITV4()    asm volatile("s_waitcnt vmcnt(4)" ::: "memory")
#define WAITV0()    asm volatile("s_waitcnt vmcnt(0)" ::: "memory")
#define WAITLGKM0() asm volatile("s_waitcnt lgkmcnt(0)" ::: "memory")
#define SBAR()      __builtin_amdgcn_s_barrier()
#define SCHED0()    __builtin_amdgcn_sched_barrier(0)
#define MFMA16(d, va, vb) d = __builtin_amdgcn_mfma_f32_16x16x32_f16(va, vb, d, 0, 0, 0)

// =============================================================================
// 256x256 tile, BK=32, 8 waves (2M x 4N), 4-buffer LDS pipeline (128 KiB),
// prefetch distance 3 tiles, counted vmcnt(8) (T3/T4).
//
// Per K-tile T (2 phases, 16 MFMA each):
//   ph1: STAGE_A(T+3); ds_read A m0-3 + B n0-3 of buf[T&3]; SBAR; lgkmcnt(0);
//        setprio(1); 16 MFMA; setprio(0); SBAR
//   ph2: STAGE_B(T+3); ds_read A m4-7; SBAR; lgkmcnt(0); setprio(1); 16 MFMA;
//        setprio(0); vmcnt(8); SBAR
//
// Ledger: stages issued during tile X target tile X+3 (4 loads per tile:
// A 2 + B 2). At end-of-tile-T wait we need tile T+1 landed; younger loads
// outstanding = tiles T+2, T+3 (8 loads) -> vmcnt(8). Tail: T==NT-3 ->
// vmcnt(4) (only T+2 younger), T>=NT-2 -> vmcnt(0). Flight time per load:
// 5-6 phases (~800-930 MFMA-cycles at 2 waves/SIMD) >= L2/L3/HBM latency.
//
// Race-freedom (barrier-ordered): tile T+3's buffer = (T-1)&3, last read at
// tile T-1; those reads completed before T-1's phase-end barriers (lgkmcnt(0)
// precedes MFMA precedes SBAR). Stages for T+3 issue during T, strictly after.
// Reads of buf[T&3] at tile T: staged during T-3, drained by the vmcnt at end
// of T-1 + SBAR.
//
// LDS swizzle: 64B rows, slot' = slot ^ ((row>>2)&3), applied as inverse-
// swizzled GLOBAL source + swizzled ds_read offset, linear gl_lds dest
// (rule #21). Gives 2 lanes/bank-quad per 16-lane group.
// =============================================================================

constexpr int BM = 256, BN = 256, BK = 32;
constexpr int NT = Kdim / BK;  // 128

__global__ __launch_bounds__(512, 2) void w8_gemm256(
    const _Float16* __restrict__ A, const _Float16* __restrict__ Bw,
    const float* __restrict__ maxval, float* __restrict__ C) {
  __shared__ _Float16 As[4][BM][BK];  // 4 x 16 KiB
  __shared__ _Float16 Bs[4][BM][BK];  // 4 x 16 KiB

  const int nbn = Ndim / BN;                    // 43
  const int cpx = ((Mdim / BM) * nbn) / 8;      // 1376/8 = 172 (bijective)
  int bid = blockIdx.x;
  bid = (bid & 7) * cpx + (bid >> 3);           // XCD-aware swizzle (T1)
  const int rowBase = (bid / nbn) * BM;
  const int colBase = (bid % nbn) * BN;

  const int t = threadIdx.x;
  const int lane = t & 63;
  const int wid = t >> 6;        // 0..7
  const int wr = wid >> 2;       // 0..1  (owns 128 output rows)
  const int wc = wid & 3;        // 0..3  (owns 64 output cols)
  const int lrow = lane & 15;
  const int kgrp = lane >> 4;    // 0..3

  // Staging: thread t owns LDS 16B slot t of each 8 KiB half-tile
  // (row sr = t>>2, slot t&3). Global source chunk is inverse-swizzled.
  const int sr = t >> 2;                              // 0..127
  const int sc = ((t & 3) ^ ((sr >> 2) & 3)) << 3;    // k-elem offset 0/8/16/24
  const size_t aRow0 = (size_t)(rowBase + sr) * Kdim + sc;
  const size_t aRow1 = (size_t)(rowBase + 128 + sr) * Kdim + sc;
  const size_t bRow0 = (size_t)(colBase + sr) * Kdim + sc;
  const size_t bRow1 = (size_t)(colBase + 128 + sr) * Kdim + sc;
  const int ldsOff = t * 8;  // f16 units; +4096 for half 1

#define STAGE_A(buf, k0) do { \
    gl_lds16(A + aRow0 + (k0), (_Float16*)As[buf] + ldsOff); \
    gl_lds16(A + aRow1 + (k0), (_Float16*)As[buf] + 4096 + ldsOff); } while (0)
#define STAGE_B(buf, k0) do { \
    gl_lds16(Bw + bRow0 + (k0), (_Float16*)Bs[buf] + ldsOff); \
    gl_lds16(Bw + bRow1 + (k0), (_Float16*)Bs[buf] + 4096 + ldsOff); } while (0)

  // Swizzled ds_read byte offsets (constant-indexed -> registers)
  int offA[8], offB[4];
#pragma unroll
  for (int m = 0; m < 8; ++m) {
    int rt = wr * 128 + m * 16 + lrow;
    offA[m] = rt * 64 + ((kgrp ^ ((rt >> 2) & 3)) << 4);
  }
#pragma unroll
  for (int n = 0; n < 4; ++n) {
    int rt = wc * 64 + n * 16 + lrow;
    offB[n] = rt * 64 + ((kgrp ^ ((rt >> 2) & 3)) << 4);
  }

#define RDA(buf, m) (*(const f16x8*)((const char*)&As[buf][0][0] + offA[m]))
#define RDB(buf, n) (*(const f16x8*)((const char*)&Bs[buf][0][0] + offB[n]))

  f32x4 acc[8][4] = {};

  // Prologue: tiles 0,1,2 -> bufs 0,1,2 (12 loads); drain tile0 (vmcnt(8)).
  STAGE_A(0, 0);      STAGE_B(0, 0);
  STAGE_A(1, BK);     STAGE_B(1, BK);
  STAGE_A(2, 2 * BK); STAGE_B(2, 2 * BK);
  WAITV8();
  SBAR();

  for (int T = 0; T < NT; ++T) {
    const int cur = T & 3;
    const int nx3 = (T + 3) & 3;
    const int kst = (T + 3) * BK;
    // ---- phase 1: stage A(T+3); read A m0-3 + B n0-3; MFMA m0-3 x n0-3
    if (T + 3 < NT) STAGE_A(nx3, kst);
    f16x8 a0 = RDA(cur, 0), a1 = RDA(cur, 1), a2 = RDA(cur, 2), a3 = RDA(cur, 3);
    f16x8 b0 = RDB(cur, 0), b1 = RDB(cur, 1), b2 = RDB(cur, 2), b3 = RDB(cur, 3);
    SBAR();
    WAITLGKM0();
    SCHED0();
    __builtin_amdgcn_s_setprio(1);
    MFMA16(acc[0][0], a0, b0); MFMA16(acc[0][1], a0, b1); MFMA16(acc[0][2], a0, b2); MFMA16(acc[0][3], a0, b3);
    MFMA16(acc[1][0], a1, b0); MFMA16(acc[1][1], a1, b1); MFMA16(acc[1][2], a1, b2); MFMA16(acc[1][3], a1, b3);
    MFMA16(acc[2][0], a2, b0); MFMA16(acc[2][1], a2, b1); MFMA16(acc[2][2], a2, b2); MFMA16(acc[2][3], a2, b3);
    MFMA16(acc[3][0], a3, b0); MFMA16(acc[3][1], a3, b1); MFMA16(acc[3][2], a3, b2); MFMA16(acc[3][3], a3, b3);
    __builtin_amdgcn_s_setprio(0);
    SBAR();
    // ---- phase 2: stage B(T+3); read A m4-7; MFMA m4-7 x n0-3 (reuse b0-3)
    if (T + 3 < NT) STAGE_B(nx3, kst);
    f16x8 a4 = RDA(cur, 4), a5 = RDA(cur, 5), a6 = RDA(cur, 6), a7 = RDA(cur, 7);
    SBAR();
    WAITLGKM0();
    SCHED0();
    __builtin_amdgcn_s_setprio(1);
    MFMA16(acc[4][0], a4, b0); MFMA16(acc[4][1], a4, b1); MFMA16(acc[4][2], a4, b2); MFMA16(acc[4][3], a4, b3);
    MFMA16(acc[5][0], a5, b0); MFMA16(acc[5][1], a5, b1); MFMA16(acc[5][2], a5, b2); MFMA16(acc[5][3], a5, b3);
    MFMA16(acc[6][0], a6, b0); MFMA16(acc[6][1], a6, b1); MFMA16(acc[6][2], a6, b2); MFMA16(acc[6][3], a6, b3);
    MFMA16(acc[7][0], a7, b0); MFMA16(acc[7][1], a7, b1); MFMA16(acc[7][2], a7, b2); MFMA16(acc[7][3], a7, b3);
    __builtin_amdgcn_s_setprio(0);
    // end-of-tile: tile T+1 must be landed before next iteration reads it.
    // Younger outstanding: tiles T+2, T+3 (if staged) -> 8 / 4 / 0.
    if (T < NT - 3)       { WAITV8(); }
    else if (T == NT - 3) { WAITV4(); }
    else                  { WAITV0(); }
    SBAR();
  }

  // Epilogue: C/D layout col=lane&15, row=(lane>>4)*4+reg (m89-verified).
  float s[4];
#pragma unroll
  for (int n = 0; n < 4; ++n)
    s[n] = maxval[colBase + wc * 64 + n * 16 + lrow] * (1.0f / 127.0f);
#pragma unroll
  for (int m = 0; m < 8; ++m) {
#pragma unroll
    for (int j = 0; j < 4; ++j) {
      int row = rowBase + wr * 128 + m * 16 + kgrp * 4 + j;
      float* cp = C + (size_t)row * Ndim + colBase + wc * 64 + lrow;
#pragma unroll
      for (int n = 0; n < 4; ++n)
        cp[n * 16] = acc[m][n][j] * s[n];
    }
  }
#undef STAGE_A
#undef STAGE_B
#undef RDA
#undef RDB
}

// ---------------- fallback (ws too small): 128^2 reg-staged convert-in-GEMM ---

__global__ __launch_bounds__(256) void w8_gemm_fb(const float* __restrict__ A,
                                                  const int* __restrict__ Bw,
                                                  const float* __restrict__ maxval,
                                                  float* __restrict__ C) {
  __shared__ _Float16 Asb[128][32];
  __shared__ _Float16 Bsb[128][32];
  const int nbn = Ndim / 128;
  const int cpx = ((Mdim / 128) * nbn) / 8;
  int bid = blockIdx.x;
  bid = (bid & 7) * cpx + (bid >> 3);
  const int rowBase = (bid / nbn) * 128;
  const int colBase = (bid % nbn) * 128;
  const int t = threadIdx.x;
  const int lane = t & 63;
  const int wid = t >> 6;
  const int wr = wid >> 1, wc = wid & 1;
  const int lrow = lane & 15, kgrp = lane >> 4;
  f32x4 acc[4][4] = {};
  for (int k0 = 0; k0 < Kdim; k0 += 32) {
    __syncthreads();
#pragma unroll
    for (int i = 0; i < 4; ++i) {
      int c = i * 256 + t;
      int r = c >> 3;
      int ce = (c & 7) * 4;
      f32x4 av = *(const f32x4*)(A + (size_t)(rowBase + r) * Kdim + k0 + ce);
      i32x4 bv = *(const i32x4*)(Bw + (size_t)(colBase + r) * Kdim + k0 + ce);
      f16x4 ah, bh;
#pragma unroll
      for (int j = 0; j < 4; ++j) { ah[j] = (_Float16)av[j]; bh[j] = (_Float16)bv[j]; }
      *(f16x4*)&Asb[r][ce] = ah;
      *(f16x4*)&Bsb[r][ce] = bh;
    }
    __syncthreads();
    f16x8 a[4], b[4];
#pragma unroll
    for (int m = 0; m < 4; ++m) a[m] = *(const f16x8*)&Asb[wr * 64 + m * 16 + lrow][kgrp * 8];
#pragma unroll
    for (int n = 0; n < 4; ++n) b[n] = *(const f16x8*)&Bsb[wc * 64 + n * 16 + lrow][kgrp * 8];
#pragma unroll
    for (int m = 0; m < 4; ++m)
#pragma unroll
      for (int n = 0; n < 4; ++n)
        acc[m][n] = __builtin_amdgcn_mfma_f32_16x16x32_f16(a[m], b[n], acc[m][n], 0, 0, 0);
  }
  float s[4];
#pragma unroll
  for (int n = 0; n < 4; ++n)
    s[n] = maxval[colBase + wc * 64 + n * 16 + lrow] * (1.0f / 127.0f);
#pragma unroll
  for (int m = 0; m < 4; ++m)
#pragma unroll
    for (int j = 0; j < 4; ++j) {
      int row = rowBase + wr * 64 + m * 16 + kgrp * 4 + j;
      float* cp = C + (size_t)row * Ndim + colBase + wc * 64 + lrow;
#pragma unroll
      for (int n = 0; n < 4; ++n) cp[n * 16] = acc[m][n][j] * s[n];
    }
}

// ---------------- launch ------------------------------------------------------

extern "C" void kernel_launch(void* const* d_in, const int* in_sizes, int n_in,
                              void* d_out, int out_size, void* d_ws, size_t ws_size,
                              hipStream_t stream) {
  const float* x  = (const float*)d_in[0];   // [8192, 4096] fp32
  const int*   wq = (const int*)d_in[1];     // [11008, 4096] int32
  const float* mx = (const float*)d_in[2];   // [11008] fp32
  float* out = (float*)d_out;                // [8192, 11008] fp32

  const size_t xh_bytes = (size_t)Mdim * Kdim * sizeof(_Float16);  // 64 MiB
  const size_t wh_bytes = (size_t)Ndim * Kdim * sizeof(_Float16);  // 86 MiB

  if (ws_size >= xh_bytes + wh_bytes) {
    _Float16* xh = (_Float16*)d_ws;
    _Float16* wh = (_Float16*)((char*)d_ws + xh_bytes);
    cvt_f32_f16<<<2048, 256, 0, stream>>>(x, xh, Mdim * Kdim / 8);
    cvt_i32_f16<<<2048, 256, 0, stream>>>(wq, wh, Ndim * Kdim / 8);
    const int nblocks = (Mdim / BM) * (Ndim / BN);  // 1376
    w8_gemm256<<<nblocks, 512, 0, stream>>>(xh, wh, mx, out);
  } else {
    const int nblocks = (Mdim / 128) * (Ndim / 128);
    w8_gemm_fb<<<nblocks, 256, 0, stream>>>(x, wq, mx, out);
  }
}